// Round 9
// baseline (274.900 us; speedup 1.0000x reference)
//
#include <hip/hip_runtime.h>
#include <hip/hip_bf16.h>
#include <stdint.h>

// GPT causal self-attention block. B=8, T=1024, C=768, H=8, D=96. f32 I/O.
// bf16 MFMA pipeline with fp32 accumulation. Causal mask input ignored.
//
// R8: gemm_qkv ported to the 256x256 8-phase schedule (T3+T4+T2+T5):
// BK=64, 512 threads (8 waves 2Mx4N, 128x64 per wave), 128 KB LDS dbuf,
// one 16 KB half-tile staged per phase (region whose readers retired the
// previous phase), counted vmcnt(4) at phases 4 and 8 only, st_16x32 LDS
// swizzle via pre-swizzled global source + XOR'd ds_read.
// proj / attn / cvt3 unchanged from R7.

typedef unsigned short ushort_t;
typedef __attribute__((ext_vector_type(8))) short short8;     // 8 bf16 = 4 VGPRs
typedef __attribute__((ext_vector_type(4))) float floatx4;    // MFMA C/D frag
typedef __attribute__((ext_vector_type(4))) unsigned short ushort4v;

#define MFMA16(a, b, c) __builtin_amdgcn_mfma_f32_16x16x32_bf16(a, b, c, 0, 0, 0)
#define NEG_BIG (-1e30f)

__device__ __forceinline__ unsigned short f2bf(float f) {
  union { float f; unsigned int u; } v; v.f = f;
  unsigned int r = (v.u + 0x7FFFu + ((v.u >> 16) & 1u)) >> 16;  // RNE
  return (unsigned short)r;
}

__device__ __forceinline__ unsigned int packbf2(float a, float b) {
  union { __hip_bfloat162 h; unsigned int u; } cv;
  cv.h = __float22bfloat162_rn(make_float2(a, b));
  return cv.u;
}

#define GLOAD16(src, dst)                                              \
  __builtin_amdgcn_global_load_lds(                                    \
      (const __attribute__((address_space(1))) void*)(src),            \
      (__attribute__((address_space(3))) void*)(dst), 16, 0, 0)

#define WAITBAR(VM)                                                    \
  do {                                                                 \
    asm volatile("s_waitcnt vmcnt(" #VM ")" ::: "memory");             \
    __builtin_amdgcn_s_barrier();                                      \
  } while (0)

#define WAITBAR_LGKM(VM)                                               \
  do {                                                                 \
    asm volatile("s_waitcnt vmcnt(" #VM ") lgkmcnt(0)" ::: "memory");  \
    __builtin_amdgcn_s_barrier();                                      \
  } while (0)

// ---------------------------------------------------------------------------
// Fused f32->bf16 conversion for x, Wqkv, Wproj in one launch.
// ---------------------------------------------------------------------------
__global__ __launch_bounds__(256) void cvt3(
    const float* __restrict__ x, const float* __restrict__ wa,
    const float* __restrict__ wp, ushort_t* __restrict__ xb,
    ushort_t* __restrict__ wab, ushort_t* __restrict__ wpb)
{
  const int n1 = (8192 * 768) / 4, n2 = (2304 * 768) / 4;
  int i = blockIdx.x * 256 + threadIdx.x;
  const float* in; ushort_t* out;
  if (i < n1)            { in = x;  out = xb; }
  else if (i < n1 + n2)  { in = wa; out = wab; i -= n1; }
  else                   { in = wp; out = wpb; i -= (n1 + n2); }
  float4 v = *(const float4*)(in + (size_t)i * 4);
  ushort4v o;
  o.x = f2bf(v.x); o.y = f2bf(v.y); o.z = f2bf(v.z); o.w = f2bf(v.w);
  *(ushort4v*)(out + (size_t)i * 4) = o;
}

// ===========================================================================
// gemm_qkv: 256x256 tile, BK=64, 8-phase schedule. K = 768 -> 12 K-tiles,
// 6 unrolled iterations of 2 tiles (buf0 = even tile, buf1 = odd tile).
//
// Stage regions (16 KB halves, disjoint from same-phase reads):
//   A-ev  = rows {0-63,128-191}   (read by mh=0 phases)
//   A-odd = rows {64-127,192-255} (mh=1 phases)
//   B-n0  = rows {0-31,64-95,128-159,192-223} (nh=0 phases)
//   B-n1  = +32                                (nh=1 phases)
// Iter j (phases p1..p8 = (mh,nh) of tile 2j in buf0 then 2j+1 in buf1):
//   p1: stage A-odd+B-n1(2j+1)->buf1   p3: A-ev(2j+2)->buf0
//   p4: B-n0(2j+2); vmcnt(4)           p5: A-odd(2j+2)
//   p6: B-n1(2j+2)                     p7: A-ev(2j+3)->buf1
//   p8: B-n0(2j+3); vmcnt(4)
// At each wait the halves read in the next 4 phases are exactly forced
// landed (verified by FIFO count); loads never drain to 0 until the tail.
// Swizzle: source col esrc = ecol ^ ((tid>>5)&1)<<4; read col ^ ((l15>>2)&1)<<4.
// ===========================================================================
#define STG_A(BUF, PART, T)                                            \
  do {                                                                 \
    const int r0_ = (PART) * 64 + arow0;                               \
    GLOAD16(Ag + (size_t)(m0 + r0_) * 768 + (T) * 64 + esrc,           \
            &Ab[BUF][r0_ * 64 + ecol]);                                \
    GLOAD16(Ag + (size_t)(m0 + r0_ + 128) * 768 + (T) * 64 + esrc,     \
            &Ab[BUF][(r0_ + 128) * 64 + ecol]);                        \
  } while (0)

#define STG_B(BUF, PART, T)                                            \
  do {                                                                 \
    const int r0_ = (PART) * 32 + brow0;                               \
    GLOAD16(Bg + (size_t)(n0 + r0_) * 768 + (T) * 64 + esrc,           \
            &Bb[BUF][r0_ * 64 + ecol]);                                \
    GLOAD16(Bg + (size_t)(n0 + r0_ + 128) * 768 + (T) * 64 + esrc,     \
            &Bb[BUF][(r0_ + 128) * 64 + ecol]);                        \
  } while (0)

#define PHASE(BUF, MH, NH, STAGE_CODE, WAIT_CODE)                      \
  do {                                                                 \
    short8 af_[4][2], bf_[2][2];                                       \
    _Pragma("unroll")                                                  \
    for (int i_ = 0; i_ < 4; ++i_)                                     \
      _Pragma("unroll")                                                \
      for (int k_ = 0; k_ < 2; ++k_)                                   \
        af_[i_][k_] = *(const short8*)&Ab[BUF][                        \
            (wm2 * 128 + ((MH) * 4 + i_) * 16 + l15) * 64 +            \
            ((k_ * 32 + quad * 8) ^ swzr)];                            \
    _Pragma("unroll")                                                  \
    for (int n_ = 0; n_ < 2; ++n_)                                     \
      _Pragma("unroll")                                                \
      for (int k_ = 0; k_ < 2; ++k_)                                   \
        bf_[n_][k_] = *(const short8*)&Bb[BUF][                        \
            (wn4 * 64 + ((NH) * 2 + n_) * 16 + l15) * 64 +             \
            ((k_ * 32 + quad * 8) ^ swzr)];                            \
    STAGE_CODE;                                                        \
    asm volatile("" ::: "memory");                                     \
    __builtin_amdgcn_s_barrier();                                      \
    __builtin_amdgcn_s_setprio(1);                                     \
    _Pragma("unroll")                                                  \
    for (int i_ = 0; i_ < 4; ++i_)                                     \
      _Pragma("unroll")                                                \
      for (int n_ = 0; n_ < 2; ++n_)                                   \
        _Pragma("unroll")                                              \
        for (int k_ = 0; k_ < 2; ++k_)                                 \
          acc[(MH) * 4 + i_][(NH) * 2 + n_] =                          \
              MFMA16(af_[i_][k_], bf_[n_][k_],                         \
                     acc[(MH) * 4 + i_][(NH) * 2 + n_]);               \
    __builtin_amdgcn_s_setprio(0);                                     \
    WAIT_CODE;                                                         \
    asm volatile("" ::: "memory");                                     \
    __builtin_amdgcn_s_barrier();                                      \
  } while (0)

__global__ __launch_bounds__(512) void gemm_qkv(
    const ushort_t* __restrict__ Ag,  // 8192 x 768 bf16 (x)
    const ushort_t* __restrict__ Bg,  // 2304 x 768 bf16 (Wqkv)
    const float* __restrict__ bias,   // 2304 f32
    ushort_t* __restrict__ QK,        // 8192 x 1536 bf16
    ushort_t* __restrict__ VT)        // (64 bh) x 96 x 1024 bf16 (perm cols)
{
  __shared__ ushort_t Ab[2][256 * 64];
  __shared__ ushort_t Bb[2][256 * 64];

  const int tid  = threadIdx.x;
  const int lane = tid & 63;
  const int l15  = lane & 15;
  const int quad = lane >> 4;
  const int wid  = tid >> 6;        // 0..7
  const int wm2  = wid >> 2;        // 0..1
  const int wn4  = wid & 3;         // 0..3

  // bijective XCD swizzle over 288 blocks (288 % 8 == 0)
  const int lin = blockIdx.x + blockIdx.y * 32;
  const int swz = (lin & 7) * 36 + (lin >> 3);
  const int m0 = (swz & 31) * 256;
  const int n0 = (swz >> 5) * 256;

  // staging constants
  const int arow0 = tid >> 3;                                   // 0..63
  const int brow0 = ((tid >> 3) & 31) + (((tid >> 3) >> 5) << 6);
  const int ecol  = (tid & 7) << 3;
  const int esrc  = ecol ^ (((tid >> 5) & 1) << 4);
  const int swzr  = ((l15 >> 2) & 1) << 4;

  floatx4 acc[8][4] = {};

  // prologue: tile0 all halves, tile1 {A-ev, B-n0}; force tile0 landed.
  STG_A(0, 0, 0); STG_A(0, 1, 0); STG_B(0, 0, 0); STG_B(0, 1, 0);
  STG_A(1, 0, 1); STG_B(1, 0, 1);
  WAITBAR(4);

#pragma unroll
  for (int j = 0; j < 6; ++j) {
    const int t1 = 2 * j + 1, t2 = 2 * j + 2, t3 = 2 * j + 3;
    const bool s2 = (j < 5);
    PHASE(0, 0, 0, { STG_A(1, 1, t1); STG_B(1, 1, t1); }, );
    PHASE(0, 0, 1, , );
    PHASE(0, 1, 0, { if (s2) STG_A(0, 0, t2); }, );
    PHASE(0, 1, 1, { if (s2) STG_B(0, 0, t2); },
          { if (s2) asm volatile("s_waitcnt vmcnt(4)" ::: "memory");
            else    asm volatile("s_waitcnt vmcnt(0)" ::: "memory"); });
    PHASE(1, 0, 0, { if (s2) STG_A(0, 1, t2); }, );
    PHASE(1, 0, 1, { if (s2) STG_B(0, 1, t2); }, );
    PHASE(1, 1, 0, { if (s2) STG_A(1, 0, t3); }, );
    PHASE(1, 1, 1, { if (s2) STG_B(1, 0, t3); },
          { if (s2) asm volatile("s_waitcnt vmcnt(4)" ::: "memory"); });
  }

  const float QSCALE = 0.10206207261596577f * 1.4426950408889634f;

#pragma unroll
  for (int fn = 0; fn < 4; ++fn) {
    const int gc = n0 + wn4 * 64 + fn * 16 + l15;
    const float bv = bias[gc];
    const bool isv = (gc >= 1536);
    const bool isq = (gc < 768);
    const int hh = (gc - 1536) / 96, dd = (gc - 1536) % 96;
#pragma unroll
    for (int fm = 0; fm < 8; ++fm) {
      const int gr = m0 + wm2 * 128 + fm * 16 + quad * 4;
#pragma unroll
      for (int r = 0; r < 4; ++r) {
        float val = acc[fm][fn][r] + bv;
        const int row = gr + r;
        if (!isv) {
          if (isq) val *= QSCALE;
          QK[(size_t)row * 1536 + gc] = f2bf(val);
        } else {
          const int bb = row >> 10, tt = row & 1023;
          const int tt2 = (tt & ~0x1C) | (((tt >> 4) & 1) << 2) |
                          (((tt >> 2) & 3) << 3);
          VT[(((size_t)(bb * 8 + hh)) * 96 + dd) * 1024 + tt2] = f2bf(val);
        }
      }
    }
  }
}

// ---------------------------------------------------------------------------
// Generic GEMM (proj): R7 structure (128x128, 2 LDS buffers, counted vmcnt).
// ---------------------------------------------------------------------------
#define GSTAGE(LA, LB, OFF)                                            \
  do {                                                                 \
    GLOAD16(gA + (OFF), &LA[wid * 512]);                               \
    GLOAD16(gA + (OFF) + (size_t)64 * 768, &LA[wid * 512 + 64 * 32]);  \
    GLOAD16(gB + (OFF), &LB[wid * 512]);                               \
    GLOAD16(gB + (OFF) + (size_t)64 * 768, &LB[wid * 512 + 64 * 32]);  \
  } while (0)

#define GSTEP(LA, LB, OFF, STG, VM)                                    \
  do {                                                                 \
    asm volatile("s_waitcnt vmcnt(" #VM ")" ::: "memory");             \
    __builtin_amdgcn_s_barrier();                                      \
    short8 af[4], bf[4];                                               \
    _Pragma("unroll")                                                  \
    for (int t_ = 0; t_ < 4; ++t_) {                                   \
      af[t_] = *(const short8*)&LA[(wm + t_ * 16 + l15) * 32 + sw];    \
      bf[t_] = *(const short8*)&LB[(wn + t_ * 16 + l15) * 32 + sw];    \
    }                                                                  \
    asm volatile("s_waitcnt lgkmcnt(0)" ::: "memory");                 \
    __builtin_amdgcn_s_barrier();                                      \
    if (STG) GSTAGE(LA, LB, OFF);                                      \
    __builtin_amdgcn_s_setprio(1);                                     \
    _Pragma("unroll")                                                  \
    for (int tm = 0; tm < 4; ++tm)                                     \
      _Pragma("unroll")                                                \
      for (int tn = 0; tn < 4; ++tn)                                   \
        acc[tm][tn] = MFMA16(af[tm], bf[tn], acc[tm][tn]);             \
    __builtin_amdgcn_s_setprio(0);                                     \
  } while (0)

#define GK2(T)                                                         \
  GSTEP(As0, Bs0, ((T) + 2) * 32, 1, 4);                               \
  GSTEP(As1, Bs1, ((T) + 3) * 32, 1, 4);

#define GEMM_KLOOP                                                     \
  GSTAGE(As0, Bs0, 0); GSTAGE(As1, Bs1, 32);                           \
  GK2(0) GK2(2) GK2(4) GK2(6) GK2(8) GK2(10)                           \
  GK2(12) GK2(14) GK2(16) GK2(18) GK2(20)                              \
  GSTEP(As0, Bs0, 0, 0, 4);                                            \
  GSTEP(As1, Bs1, 0, 0, 0);

__global__ __launch_bounds__(256) void gemm_proj(
    const ushort_t* __restrict__ A,   // M x 768 bf16
    const ushort_t* __restrict__ W,   // N x 768 bf16
    const float* __restrict__ bias,   // N f32
    float* __restrict__ C,            // M x N f32
    int M, int N)
{
  __shared__ ushort_t As0[128 * 32], As1[128 * 32];
  __shared__ ushort_t Bs0[128 * 32], Bs1[128 * 32];
  const int tid  = threadIdx.x;
  const int lane = tid & 63;
  const int l15  = lane & 15;
  const int quad = lane >> 4;
  const int wid  = tid >> 6;
  const int m0 = blockIdx.x * 128;
  const int n0 = blockIdx.y * 128;
  const int wm = (wid >> 1) * 64;
  const int wn = (wid & 1) * 64;
  const int srow = tid >> 2;
  const int scol = (((tid & 3) ^ ((srow ^ (srow >> 2)) & 3))) * 8;
  const int sw = (quad ^ ((l15 ^ (l15 >> 2)) & 3)) * 8;
  floatx4 acc[4][4] = {};

  const ushort_t* gA = A + (size_t)(m0 + srow) * 768 + scol;
  const ushort_t* gB = W + (size_t)(n0 + srow) * 768 + scol;

  GEMM_KLOOP;

#pragma unroll
  for (int tn = 0; tn < 4; ++tn) {
    const int gc = n0 + wn + tn * 16 + l15;
    const float bv = bias[gc];
#pragma unroll
    for (int tm = 0; tm < 4; ++tm) {
      const int gr = m0 + wm + tm * 16 + quad * 4;
#pragma unroll
      for (int r = 0; r < 4; ++r)
        C[(size_t)(gr + r) * N + gc] = acc[tm][tn][r] + bv;
    }
  }
}

// ---------------------------------------------------------------------------
// Fused causal flash attention (R6/R7 structure, unchanged).
// ---------------------------------------------------------------------------
#define ATTN_COMPUTE(KS, VTC, K0)                                      \
  do {                                                                 \
    floatx4 s[4] = {};                                                 \
    __builtin_amdgcn_s_setprio(1);                                     \
    _Pragma("unroll")                                                  \
    for (int t = 0; t < 4; ++t) {                                      \
      _Pragma("unroll")                                                \
      for (int c = 0; c < 3; ++c) {                                    \
        short8 kf = *(const short8*)                                   \
            &KS[(t * 16 + l15) * 96 + c * 32 + quad * 8];              \
        s[t] = MFMA16(kf, qf[c], s[t]);                                \
      }                                                                \
    }                                                                  \
    __builtin_amdgcn_s_setprio(0);                                     \
    float p[4][4];                                                     \
    if ((K0) + 64 <= q0w) {                                            \
      _Pragma("unroll")                                                \
      for (int t = 0; t < 4; ++t)                                      \
        _Pragma("unroll")                                              \
        for (int j = 0; j < 4; ++j) p[t][j] = s[t][j];                 \
    } else {                                                           \
      const int kq = (K0) + quad * 4;                                  \
      _Pragma("unroll")                                                \
      for (int t = 0; t < 4; ++t)                                      \
        _Pragma("unroll")                                              \
        for (int j = 0; j < 4; ++j)                                    \
          p[t][j] = (kq + t * 16 + j <= rq) ? s[t][j] : NEG_BIG;       \
    }                                                                  \
    float m0v = fmaxf(fmaxf(p[0][0], p[0][1]), fmaxf(p[0][2], p[0][3]));\
    float m1v = fmaxf(fmaxf(p[1][0], p[1][1]), fmaxf(p[1][2], p[1][3]));\
    float m2v = fmaxf(fmaxf(p[2][0], p[2][1]), fmaxf(p[2][2], p[2][3]));\
    float m3v = fmaxf(fmaxf(p[3][0], p[3][1]), fmaxf(p[3][2], p[3][3]));\
    float mt = fmaxf(fmaxf(m0v, m1v), fmaxf(m2v, m3v));                \
    mt = fmaxf(mt, __shfl_xor(mt, 16));                                \
    mt = fmaxf(mt, __shfl_xor(mt, 32));                                \
    if (!__all(mt - m_i <= 8.0f)) {                                    \
      const float mn = fmaxf(m_i, mt);                                 \
      const float al = __builtin_amdgcn_exp2f(m_i - mn);               \
      m_i = mn;                                                        \
      l_i *= al;                                                       \
      _Pragma("unroll")                                                \
      for (int j = 0; j < 4; ++j) {                                    \
        const float alr = __shfl(al, quad * 4 + j);                    \
        _Pragma("unroll")                                              \
        for (int f = 0; f < 6; ++f) O[f][j] *= alr;                    \
      }                                                                \
    }                                                                  \
    float rs = 0.f;                                                    \
    _Pragma("unroll")                                                  \
    for (int t = 0; t < 4; ++t)                                        \
      _Pragma("unroll")                                                \
      for (int j = 0; j < 4; ++j) {                                    \
        p[t][j] = __builtin_amdgcn_exp2f(p[t][j] - m_i);               \
        rs += p[t][j];                                                 \
      }                                                                \
    rs += __shfl_xor(rs, 16);                                          \
    rs += __shfl_xor(rs, 32);                                          \
    l_i += rs;                                                         \
    union { short8 s8; unsigned int u[4]; } pf0, pf1;                  \
    pf0.u[0] = packbf2(p[0][0], p[0][1]);                              \
    pf0.u[1] = packbf2(p[0][2], p[0][3]);                              \
    pf0.u[2] = packbf2(p[1][0], p[1][1]);                              \
    pf0.u[3] = packbf2(p[1][2], p[1][3]);                              \
    pf1.u[0] = packbf2(p[2][0], p[2][1]);                              \
    pf1.u[1] = packbf2(p[2][2], p[2][3]);                              \
    pf1.u[2] = packbf2(p[3][0], p[3][1]);                              \
    pf1.u[3] = packbf2(p[3][2], p[3][3]);                              \
    __builtin_amdgcn_s_setprio(1);                                     \
    _Pragma("unroll")                                                  \
    for (int f = 0; f < 6; ++f) {                                      \
      short8 vf0 = *(const short8*)&VTC[(f * 16 + l15) * 72 + quad * 8];\
      O[f] = MFMA16(pf0.s8, vf0, O[f]);                                \
      short8 vf1 = *(const short8*)                                    \
          &VTC[(f * 16 + l15) * 72 + 32 + quad * 8];                   \
      O[f] = MFMA16(pf1.s8, vf1, O[f]);                                \
    }                                                                  \
    __builtin_amdgcn_s_setprio(0);                                     \
  } while (0)

#define AITER(KS, VTC, KSN, VTN, K0)                                   \
  do {                                                                 \
    const int k0_ = (K0);                                              \
    const int nk_ = k0_ + 64;                                          \
    WAITBAR_LGKM(3);                                                   \
    _Pragma("unroll")                                                  \
    for (int i = 0; i < 3; ++i) {                                      \
      const int e = ke0 + i * 512;                                     \
      const int kr = e / 96, kc = e % 96;                               \
      GLOAD16(QK + (rowbase + nk_ + kr) * 1536 + 768 + qoff + kc,      \
              &KSN[wid * 1536 + i * 512]);                             \
    }                                                                  \
    ATTN_COMPUTE(KS, VTC, k0_);                                        \
    _Pragma("unroll")                                                  \
    for (int g = 0; g < 3; ++g)                                        \
      *(short8*)&VTN[(g * 32 + vd) * 72 + vkc] = vreg[g];              \
    if (nk_ + 64 < kend) {                                             \
      _Pragma("unroll")                                                \
      for (int g = 0; g < 3; ++g)                                      \
        vreg[g] = *(const short8*)                                     \
            (vtb + (size_t)(g * 32 + vd) * 1024 + nk_ + 64 + vkc);     \
    }                                                                  \
  } while (0)

#define AITER_LAST(KS, VTC, K0)                                        \
  do {                                                                 \
    WAITBAR_LGKM(0);                                                   \
    ATTN_COMPUTE(KS, VTC, (K0));                                       \
  } while (0)

__global__ __launch_bounds__(256) void attn_fused(
    const ushort_t* __restrict__ QK,   // (B*T) x 1536 bf16  [q*scale | k]
    const ushort_t* __restrict__ VT,   // (64 bh) x 96 x 1024 bf16 (perm cols)
    ushort_t* __restrict__ y)          // (B*T) x 768 bf16
{
  __shared__ ushort_t Ks0[64 * 96], Ks1[64 * 96];
  __shared__ ushort_t Vt0[96 * 72], Vt1[96 * 72];

  const int tid  = threadIdx.x;
  const int lane = tid & 63;
  const int l15  = lane & 15;
  const int quad = lane >> 4;
  const int wid  = tid >> 6;

  const int lin = blockIdx.x + (blockIdx.y << 4);
  const int swz = ((lin & 7) << 7) + (lin >> 3);
  const int chunk = swz & 15;
  const int bh = swz >> 4;
  const int b = bh >> 3;
  const int h = bh & 7;
  const int qoff = h * 96;

  const int q0w = chunk * 64 + wid * 16;
  const int kend = chunk * 64 + 64;
  const int rq = q0w + l15;

  const size_t rowbase = (size_t)b * 1024;
  const ushort_t* vtb = VT + (size_t)bh * 96 * 1024;

  const int ke0 = wid * 1536 + lane * 8;
  const int vd  = (tid >> 3);
  const int vkc = (tid & 7) * 8;

  short8 qf[3];
#pragma unroll
  for (int c = 0; c < 3; ++c)
    qf[c] = *(const short8*)(QK + (rowbase + q0w + l15) * 1536 + qoff +
                             c * 32 + quad * 8);

  float m_i = NEG_BIG;
  float l_i = 0.f;
  floatx4 O[6] = {};

  short8 vreg[3];

#pragma unroll
  for (int g = 0; g < 3; ++g)
    vreg[g] = *(const short8*)(vtb + (size_t)(g * 32 + vd) * 1024 + vkc);
#pragma unroll
  for (int i = 0; i < 3; ++i) {
    const int e = ke0 + i * 512;
    const int kr = e / 96, kc = e % 96;
    GLOAD16(QK + (rowbase + kr) * 1536 + 768 + qoff + kc,
            &Ks0[wid * 1536 + i * 512]);
  }
#pragma unroll
  for (int g = 0; g < 3; ++g)
    *(short8*)&Vt0[(g * 32 + vd) * 72 + vkc] = vreg[g];
#pragma unroll
  for (int g = 0; g < 3; ++g)
    vreg[g] = *(const short8*)(vtb + (size_t)(g * 32 + vd) * 1024 + 64 + vkc);

  int k0 = 0;
  while (k0 + 128 < kend) {
    AITER(Ks0, Vt0, Ks1, Vt1, k0);
    AITER(Ks1, Vt1, Ks0, Vt0, k0 + 64);
    k0 += 128;
  }
  if (k0 + 64 < kend) {
    AITER(Ks0, Vt0, Ks1, Vt1, k0);
    AITER_LAST(Ks1, Vt1, k0 + 64);
  } else {
    AITER_LAST(Ks0, Vt0, k0);
  }

  float inv[4];
#pragma unroll
  for (int j = 0; j < 4; ++j) {
    const float lj = __shfl(l_i, quad * 4 + j);
    inv[j] = 1.0f / fmaxf(lj, 1e-20f);
  }
#pragma unroll
  for (int j = 0; j < 4; ++j) {
    const size_t row = rowbase + q0w + quad * 4 + j;
#pragma unroll
    for (int f = 0; f < 6; ++f)
      y[row * 768 + qoff + f * 16 + l15] = f2bf(O[f][j] * inv[j]);
  }
}

// ---------------------------------------------------------------------------
extern "C" void kernel_launch(void* const* d_in, const int* in_sizes, int n_in,
                              void* d_out, int out_size, void* d_ws, size_t ws_size,
                              hipStream_t stream)
{
  const float* x_f  = (const float*)d_in[0];
  const float* wa_f = (const float*)d_in[1];
  const float* ba_f = (const float*)d_in[2];
  const float* wp_f = (const float*)d_in[3];
  const float* bp_f = (const float*)d_in[4];
  float* out = (float*)d_out;

  ushort_t* xb  = (ushort_t*)d_ws;                    // 8192 x  768
  ushort_t* wab = xb  + (size_t)8192 * 768;           // 2304 x  768
  ushort_t* wpb = wab + (size_t)2304 * 768;           //  768 x  768
  ushort_t* QK  = wpb + (size_t)768 * 768;            // 8192 x 1536
  ushort_t* VT  = QK  + (size_t)8192 * 1536;          // 64 x 96 x 1024
  ushort_t* yw  = VT  + (size_t)8192 * 768;           // 8192 x  768

  cvt3<<<8448, 256, 0, stream>>>(x_f, wa_f, wp_f, xb, wab, wpb);

  gemm_qkv<<<dim3(32, 9), 512, 0, stream>>>(xb, wab, ba_f, QK, VT);
  attn_fused<<<dim3(16, 64), 256, 0, stream>>>(QK, VT, yw);
  gemm_proj<<<dim3(64, 6), 256, 0, stream>>>(yw, wpb, bp_f, out,
                                             8192, 768);
}

// Round 10
// 194.421 us; speedup vs baseline: 1.4139x; 1.4139x over previous
//
#include <hip/hip_runtime.h>
#include <hip/hip_bf16.h>
#include <stdint.h>

// GPT causal self-attention block. B=8, T=1024, C=768, H=8, D=96. f32 I/O.
// bf16 MFMA pipeline with fp32 accumulation. Causal mask input ignored.
//
// R9: revert to R7 structure (best: 204.7 us) after the 8-phase 256^2 port
// regressed (shape doesn't transfer: K=768 -> 12 K-tiles, 128KB LDS -> 1
// block/CU, FETCH 2.3x). qkv structure is declared at its practical level.
// Two cheap adds: (1) attn LPT scheduling - heavy q-chunks dispatch first
// (chunk = 15 - (swz&15)); (2) qkv VT epilogue packs r=0..3 into one 8B
// store (sigma preserves tt bits 0-1 -> 4 consecutive u16s).

typedef unsigned short ushort_t;
typedef __attribute__((ext_vector_type(8))) short short8;     // 8 bf16 = 4 VGPRs
typedef __attribute__((ext_vector_type(4))) float floatx4;    // MFMA C/D frag
typedef __attribute__((ext_vector_type(4))) unsigned short ushort4v;

#define MFMA16(a, b, c) __builtin_amdgcn_mfma_f32_16x16x32_bf16(a, b, c, 0, 0, 0)
#define NEG_BIG (-1e30f)

__device__ __forceinline__ unsigned short f2bf(float f) {
  union { float f; unsigned int u; } v; v.f = f;
  unsigned int r = (v.u + 0x7FFFu + ((v.u >> 16) & 1u)) >> 16;  // RNE
  return (unsigned short)r;
}

__device__ __forceinline__ unsigned int packbf2(float a, float b) {
  // low 16 = bf16(a), high 16 = bf16(b)  (v_cvt_pk_bf16_f32)
  union { __hip_bfloat162 h; unsigned int u; } cv;
  cv.h = __float22bfloat162_rn(make_float2(a, b));
  return cv.u;
}

#define GLOAD16(src, dst)                                              \
  __builtin_amdgcn_global_load_lds(                                    \
      (const __attribute__((address_space(1))) void*)(src),            \
      (__attribute__((address_space(3))) void*)(dst), 16, 0, 0)

// counted wait + raw barrier (no vmcnt(0) auto-drain like __syncthreads)
#define WAITBAR_LGKM(VM)                                               \
  do {                                                                 \
    asm volatile("s_waitcnt vmcnt(" #VM ") lgkmcnt(0)" ::: "memory");  \
    __builtin_amdgcn_s_barrier();                                      \
  } while (0)

// ---------------------------------------------------------------------------
// Fused f32->bf16 conversion for x, Wqkv, Wproj in one launch.
// ---------------------------------------------------------------------------
__global__ __launch_bounds__(256) void cvt3(
    const float* __restrict__ x, const float* __restrict__ wa,
    const float* __restrict__ wp, ushort_t* __restrict__ xb,
    ushort_t* __restrict__ wab, ushort_t* __restrict__ wpb)
{
  const int n1 = (8192 * 768) / 4, n2 = (2304 * 768) / 4;
  int i = blockIdx.x * 256 + threadIdx.x;
  const float* in; ushort_t* out;
  if (i < n1)            { in = x;  out = xb; }
  else if (i < n1 + n2)  { in = wa; out = wab; i -= n1; }
  else                   { in = wp; out = wpb; i -= (n1 + n2); }
  float4 v = *(const float4*)(in + (size_t)i * 4);
  ushort4v o;
  o.x = f2bf(v.x); o.y = f2bf(v.y); o.z = f2bf(v.z); o.w = f2bf(v.w);
  *(ushort4v*)(out + (size_t)i * 4) = o;
}

// ---------------------------------------------------------------------------
// GEMM machinery (R7): 128x128 tile, BK=32, 4 waves 2x2, 2 LDS buffers
// (32 KB), counted vmcnt(4). K = 768 (24 steps), static buffer chain.
// Step t: {vmcnt(4); bar; ds_read frags; lgkmcnt(0); bar; stage tile t+2
// into this same buffer; MFMA}.
// ---------------------------------------------------------------------------
#define GSTAGE(LA, LB, OFF)                                            \
  do {                                                                 \
    GLOAD16(gA + (OFF), &LA[wid * 512]);                               \
    GLOAD16(gA + (OFF) + (size_t)64 * 768, &LA[wid * 512 + 64 * 32]);  \
    GLOAD16(gB + (OFF), &LB[wid * 512]);                               \
    GLOAD16(gB + (OFF) + (size_t)64 * 768, &LB[wid * 512 + 64 * 32]);  \
  } while (0)

#define GSTEP(LA, LB, OFF, STG, VM)                                    \
  do {                                                                 \
    asm volatile("s_waitcnt vmcnt(" #VM ")" ::: "memory");             \
    __builtin_amdgcn_s_barrier();                                      \
    short8 af[4], bf[4];                                               \
    _Pragma("unroll")                                                  \
    for (int t_ = 0; t_ < 4; ++t_) {                                   \
      af[t_] = *(const short8*)&LA[(wm + t_ * 16 + l15) * 32 + sw];    \
      bf[t_] = *(const short8*)&LB[(wn + t_ * 16 + l15) * 32 + sw];    \
    }                                                                  \
    asm volatile("s_waitcnt lgkmcnt(0)" ::: "memory");                 \
    __builtin_amdgcn_s_barrier();                                      \
    if (STG) GSTAGE(LA, LB, OFF);                                      \
    __builtin_amdgcn_s_setprio(1);                                     \
    _Pragma("unroll")                                                  \
    for (int tm = 0; tm < 4; ++tm)                                     \
      _Pragma("unroll")                                                \
      for (int tn = 0; tn < 4; ++tn)                                   \
        acc[tm][tn] = MFMA16(af[tm], bf[tn], acc[tm][tn]);             \
    __builtin_amdgcn_s_setprio(0);                                     \
  } while (0)

// two steps t (buf0), t+1 (buf1), staging tiles t+2, t+3
#define GK2(T)                                                         \
  GSTEP(As0, Bs0, ((T) + 2) * 32, 1, 4);                               \
  GSTEP(As1, Bs1, ((T) + 3) * 32, 1, 4);

#define GEMM_KLOOP                                                     \
  GSTAGE(As0, Bs0, 0); GSTAGE(As1, Bs1, 32);                           \
  GK2(0) GK2(2) GK2(4) GK2(6) GK2(8) GK2(10)                           \
  GK2(12) GK2(14) GK2(16) GK2(18) GK2(20)                              \
  GSTEP(As0, Bs0, 0, 0, 4);                                            \
  GSTEP(As1, Bs1, 0, 0, 0);

#define GEMM_DECLS                                                     \
  __shared__ ushort_t As0[128 * 32], As1[128 * 32];                    \
  __shared__ ushort_t Bs0[128 * 32], Bs1[128 * 32];                    \
  const int tid  = threadIdx.x;                                        \
  const int lane = tid & 63;                                           \
  const int l15  = lane & 15;                                          \
  const int quad = lane >> 4;                                          \
  const int wid  = tid >> 6;                                           \
  const int m0 = blockIdx.x * 128;                                     \
  const int n0 = blockIdx.y * 128;                                     \
  const int wm = (wid >> 1) * 64;                                      \
  const int wn = (wid & 1) * 64;                                       \
  const int srow = tid >> 2;                                           \
  const int scol = (((tid & 3) ^ ((srow ^ (srow >> 2)) & 3))) * 8;     \
  const int sw = (quad ^ ((l15 ^ (l15 >> 2)) & 3)) * 8;                \
  floatx4 acc[4][4] = {};

// ---------------------------------------------------------------------------
// QKV GEMM: qkv = x @ Wqkv^T + b. Q columns pre-scaled by (1/sqrt(96))*log2e.
// Writes q,k into QK (row stride 1536) and v TRANSPOSED into VT[b][h][d][T]
// with time index sigma-permuted within each 64-block. sigma keeps tt bits
// 0-1, so the r=0..3 accumulator values pack into one aligned 8B store.
// ---------------------------------------------------------------------------
__global__ __launch_bounds__(256) void gemm_qkv(
    const ushort_t* __restrict__ A,   // 8192 x 768 bf16 (x)
    const ushort_t* __restrict__ W,   // 2304 x 768 bf16
    const float* __restrict__ bias,   // 2304 f32
    ushort_t* __restrict__ QK,        // 8192 x 1536 bf16
    ushort_t* __restrict__ VT)        // (64 bh) x 96 x 1024 bf16 (perm cols)
{
  GEMM_DECLS;

  const ushort_t* gA = A + (size_t)(m0 + srow) * 768 + scol;
  const ushort_t* gB = W + (size_t)(n0 + srow) * 768 + scol;

  GEMM_KLOOP;

  const float QSCALE = 0.10206207261596577f * 1.4426950408889634f;

#pragma unroll
  for (int tn = 0; tn < 4; ++tn) {
    const int gc = n0 + wn + tn * 16 + l15;
    const float bv = bias[gc];
    const bool isv = (gc >= 1536);          // whole 16-col tile same side
    const bool isq = (gc < 768);
    const int hh = (gc - 1536) / 96, dd = (gc - 1536) % 96;
#pragma unroll
    for (int tm = 0; tm < 4; ++tm) {
      const int gr = m0 + wm + tm * 16 + quad * 4;   // multiple of 4
      if (!isv) {
#pragma unroll
        for (int r = 0; r < 4; ++r) {
          float val = acc[tm][tn][r] + bv;
          if (isq) val *= QSCALE;
          QK[(size_t)(gr + r) * 1536 + gc] = f2bf(val);
        }
      } else {
        const int bb = gr >> 10, tt = gr & 1023;     // same bb for r=0..3
        const int tt2 = (tt & ~0x1C) | (((tt >> 4) & 1) << 2) |
                        (((tt >> 2) & 3) << 3);      // bits 0-1 preserved
        ushort4v o;
        o.x = f2bf(acc[tm][tn][0] + bv);
        o.y = f2bf(acc[tm][tn][1] + bv);
        o.z = f2bf(acc[tm][tn][2] + bv);
        o.w = f2bf(acc[tm][tn][3] + bv);
        *(ushort4v*)(VT + (((size_t)(bb * 8 + hh)) * 96 + dd) * 1024 + tt2) = o;
      }
    }
  }
}

// ---------------------------------------------------------------------------
// Generic GEMM (proj): C[m][n] = sum_k A[m][k] W[n][k] + bias[n], f32 out.
// K = 768 fixed. Same counted pipeline.
// ---------------------------------------------------------------------------
__global__ __launch_bounds__(256) void gemm_proj(
    const ushort_t* __restrict__ A,   // M x 768 bf16
    const ushort_t* __restrict__ W,   // N x 768 bf16
    const float* __restrict__ bias,   // N f32
    float* __restrict__ C,            // M x N f32
    int M, int N)
{
  GEMM_DECLS;

  const ushort_t* gA = A + (size_t)(m0 + srow) * 768 + scol;
  const ushort_t* gB = W + (size_t)(n0 + srow) * 768 + scol;

  GEMM_KLOOP;

#pragma unroll
  for (int tn = 0; tn < 4; ++tn) {
    const int gc = n0 + wn + tn * 16 + l15;
    const float bv = bias[gc];
#pragma unroll
    for (int tm = 0; tm < 4; ++tm) {
      const int gr = m0 + wm + tm * 16 + quad * 4;
#pragma unroll
      for (int r = 0; r < 4; ++r)
        C[(size_t)(gr + r) * N + gc] = acc[tm][tn][r] + bv;
    }
  }
}

// ---------------------------------------------------------------------------
// Fused causal flash attention, swapped-QK^T form, counted-vmcnt pipeline.
// Grid (16, 64); block = one 64-row q-chunk of one (b,h). chunk/bh derived
// from an XCD-swizzled linear id; LPT: heavy chunks (large kend) dispatch
// first via chunk = 15 - (swz & 15). Waves own rows chunk*64 + wid*16;
// kend = (chunk+1)*64 so every wave is active in every iteration.
// ---------------------------------------------------------------------------
#define ATTN_COMPUTE(KS, VTC, K0)                                      \
  do {                                                                 \
    floatx4 s[4] = {};                                                 \
    __builtin_amdgcn_s_setprio(1);                                     \
    _Pragma("unroll")                                                  \
    for (int t = 0; t < 4; ++t) {                                      \
      _Pragma("unroll")                                                \
      for (int c = 0; c < 3; ++c) {                                    \
        short8 kf = *(const short8*)                                   \
            &KS[(t * 16 + l15) * 96 + c * 32 + quad * 8];              \
        s[t] = MFMA16(kf, qf[c], s[t]);                                \
      }                                                                \
    }                                                                  \
    __builtin_amdgcn_s_setprio(0);                                     \
    float p[4][4];                                                     \
    if ((K0) + 64 <= q0w) {                                            \
      _Pragma("unroll")                                                \
      for (int t = 0; t < 4; ++t)                                      \
        _Pragma("unroll")                                              \
        for (int j = 0; j < 4; ++j) p[t][j] = s[t][j];                 \
    } else {                                                           \
      const int kq = (K0) + quad * 4;                                  \
      _Pragma("unroll")                                                \
      for (int t = 0; t < 4; ++t)                                      \
        _Pragma("unroll")                                              \
        for (int j = 0; j < 4; ++j)                                    \
          p[t][j] = (kq + t * 16 + j <= rq) ? s[t][j] : NEG_BIG;       \
    }                                                                  \
    float m0v = fmaxf(fmaxf(p[0][0], p[0][1]), fmaxf(p[0][2], p[0][3]));\
    float m1v = fmaxf(fmaxf(p[1][0], p[1][1]), fmaxf(p[1][2], p[1][3]));\
    float m2v = fmaxf(fmaxf(p[2][0], p[2][1]), fmaxf(p[2][2], p[2][3]));\
    float m3v = fmaxf(fmaxf(p[3][0], p[3][1]), fmaxf(p[3][2], p[3][3]));\
    float mt = fmaxf(fmaxf(m0v, m1v), fmaxf(m2v, m3v));                \
    mt = fmaxf(mt, __shfl_xor(mt, 16));                                \
    mt = fmaxf(mt, __shfl_xor(mt, 32));                                \
    if (!__all(mt - m_i <= 8.0f)) {                                    \
      const float mn = fmaxf(m_i, mt);                                 \
      const float al = __builtin_amdgcn_exp2f(m_i - mn);               \
      m_i = mn;                                                        \
      l_i *= al;                                                       \
      _Pragma("unroll")                                                \
      for (int j = 0; j < 4; ++j) {                                    \
        const float alr = __shfl(al, quad * 4 + j);                    \
        _Pragma("unroll")                                              \
        for (int f = 0; f < 6; ++f) O[f][j] *= alr;                    \
      }                                                                \
    }                                                                  \
    float rs = 0.f;                                                    \
    _Pragma("unroll")                                                  \
    for (int t = 0; t < 4; ++t)                                        \
      _Pragma("unroll")                                                \
      for (int j = 0; j < 4; ++j) {                                    \
        p[t][j] = __builtin_amdgcn_exp2f(p[t][j] - m_i);               \
        rs += p[t][j];                                                 \
      }                                                                \
    rs += __shfl_xor(rs, 16);                                          \
    rs += __shfl_xor(rs, 32);                                          \
    l_i += rs;                                                         \
    union { short8 s8; unsigned int u[4]; } pf0, pf1;                  \
    pf0.u[0] = packbf2(p[0][0], p[0][1]);                              \
    pf0.u[1] = packbf2(p[0][2], p[0][3]);                              \
    pf0.u[2] = packbf2(p[1][0], p[1][1]);                              \
    pf0.u[3] = packbf2(p[1][2], p[1][3]);                              \
    pf1.u[0] = packbf2(p[2][0], p[2][1]);                              \
    pf1.u[1] = packbf2(p[2][2], p[2][3]);                              \
    pf1.u[2] = packbf2(p[3][0], p[3][1]);                              \
    pf1.u[3] = packbf2(p[3][2], p[3][3]);                              \
    __builtin_amdgcn_s_setprio(1);                                     \
    _Pragma("unroll")                                                  \
    for (int f = 0; f < 6; ++f) {                                      \
      short8 vf0 = *(const short8*)&VTC[(f * 16 + l15) * 72 + quad * 8];\
      O[f] = MFMA16(pf0.s8, vf0, O[f]);                                \
      short8 vf1 = *(const short8*)                                    \
          &VTC[(f * 16 + l15) * 72 + 32 + quad * 8];                   \
      O[f] = MFMA16(pf1.s8, vf1, O[f]);                                \
    }                                                                  \
    __builtin_amdgcn_s_setprio(0);                                     \
  } while (0)

// one pipelined iteration (never the last): wait, stage K(t+1) into KSN,
// compute(t) from KS/VTC, write V(t+1) into VTN, load V(t+2) regs.
#define AITER(KS, VTC, KSN, VTN, K0)                                   \
  do {                                                                 \
    const int k0_ = (K0);                                              \
    const int nk_ = k0_ + 64;                                          \
    WAITBAR_LGKM(3);                                                   \
    _Pragma("unroll")                                                  \
    for (int i = 0; i < 3; ++i) {                                      \
      const int e = ke0 + i * 512;                                     \
      const int kr = e / 96, kc = e % 96;                              \
      GLOAD16(QK + (rowbase + nk_ + kr) * 1536 + 768 + qoff + kc,      \
              &KSN[wid * 1536 + i * 512]);                             \
    }                                                                  \
    ATTN_COMPUTE(KS, VTC, k0_);                                        \
    _Pragma("unroll")                                                  \
    for (int g = 0; g < 3; ++g)                                        \
      *(short8*)&VTN[(g * 32 + vd) * 72 + vkc] = vreg[g];              \
    if (nk_ + 64 < kend) {                                             \
      _Pragma("unroll")                                                \
      for (int g = 0; g < 3; ++g)                                      \
        vreg[g] = *(const short8*)                                     \
            (vtb + (size_t)(g * 32 + vd) * 1024 + nk_ + 64 + vkc);     \
    }                                                                  \
  } while (0)

#define AITER_LAST(KS, VTC, K0)                                        \
  do {                                                                 \
    WAITBAR_LGKM(0);                                                   \
    ATTN_COMPUTE(KS, VTC, (K0));                                       \
  } while (0)

__global__ __launch_bounds__(256) void attn_fused(
    const ushort_t* __restrict__ QK,   // (B*T) x 1536 bf16  [q*scale | k]
    const ushort_t* __restrict__ VT,   // (64 bh) x 96 x 1024 bf16 (perm cols)
    ushort_t* __restrict__ y)          // (B*T) x 768 bf16
{
  __shared__ ushort_t Ks0[64 * 96], Ks1[64 * 96];
  __shared__ ushort_t Vt0[96 * 72], Vt1[96 * 72];

  const int tid  = threadIdx.x;
  const int lane = tid & 63;
  const int l15  = lane & 15;
  const int quad = lane >> 4;
  const int wid  = tid >> 6;

  // XCD-swizzled work assignment + LPT: heavy chunks dispatch first.
  const int lin = blockIdx.x + (blockIdx.y << 4);
  const int swz = ((lin & 7) << 7) + (lin >> 3);
  const int chunk = 15 - (swz & 15);   // 15..0 (heavy first)
  const int bh = swz >> 4;             // 0..63
  const int b = bh >> 3;
  const int h = bh & 7;
  const int qoff = h * 96;

  const int q0w = chunk * 64 + wid * 16;   // wave's first q row
  const int kend = chunk * 64 + 64;        // block loop bound == causal bound
  const int rq = q0w + l15;                // this lane's q row

  const size_t rowbase = (size_t)b * 1024;
  const ushort_t* vtb = VT + (size_t)bh * 96 * 1024;

  // per-thread staging coords
  const int ke0 = wid * 1536 + lane * 8;           // K-stage element base
  const int vd  = (tid >> 3);                      // V-stage row within group
  const int vkc = (tid & 7) * 8;                   // V-stage col

  // Q fragments (used as B operand), K=96 in 3 chunks of 32
  short8 qf[3];
#pragma unroll
  for (int c = 0; c < 3; ++c)
    qf[c] = *(const short8*)(QK + (rowbase + q0w + l15) * 1536 + qoff +
                             c * 32 + quad * 8);

  float m_i = NEG_BIG;   // running max for row l15 (exp2 domain)
  float l_i = 0.f;       // running denom for row l15
  floatx4 O[6] = {};

  short8 vreg[3];

  // prologue: V(0) regs FIRST, K(0) gloads, write V(0), issue V(1) regs.
#pragma unroll
  for (int g = 0; g < 3; ++g)
    vreg[g] = *(const short8*)(vtb + (size_t)(g * 32 + vd) * 1024 + vkc);
#pragma unroll
  for (int i = 0; i < 3; ++i) {
    const int e = ke0 + i * 512;
    const int kr = e / 96, kc = e % 96;
    GLOAD16(QK + (rowbase + kr) * 1536 + 768 + qoff + kc,
            &Ks0[wid * 1536 + i * 512]);
  }
#pragma unroll
  for (int g = 0; g < 3; ++g)
    *(short8*)&Vt0[(g * 32 + vd) * 72 + vkc] = vreg[g];
#pragma unroll
  for (int g = 0; g < 3; ++g)
    vreg[g] = *(const short8*)(vtb + (size_t)(g * 32 + vd) * 1024 + 64 + vkc);

  // main loop: pairs of tiles with static buffers; 1-or-2 iteration tail.
  int k0 = 0;
  while (k0 + 128 < kend) {
    AITER(Ks0, Vt0, Ks1, Vt1, k0);
    AITER(Ks1, Vt1, Ks0, Vt0, k0 + 64);
    k0 += 128;
  }
  if (k0 + 64 < kend) {
    AITER(Ks0, Vt0, Ks1, Vt1, k0);
    AITER_LAST(Ks1, Vt1, k0 + 64);
  } else {
    AITER_LAST(Ks0, Vt0, k0);
  }

  // epilogue: O rows are quad*4+j; softmax denom lives in lane (row)
  float inv[4];
#pragma unroll
  for (int j = 0; j < 4; ++j) {
    const float lj = __shfl(l_i, quad * 4 + j);
    inv[j] = 1.0f / fmaxf(lj, 1e-20f);
  }
#pragma unroll
  for (int j = 0; j < 4; ++j) {
    const size_t row = rowbase + q0w + quad * 4 + j;
#pragma unroll
    for (int f = 0; f < 6; ++f)
      y[row * 768 + qoff + f * 16 + l15] = f2bf(O[f][j] * inv[j]);
  }
}

// ---------------------------------------------------------------------------
extern "C" void kernel_launch(void* const* d_in, const int* in_sizes, int n_in,
                              void* d_out, int out_size, void* d_ws, size_t ws_size,
                              hipStream_t stream)
{
  const float* x_f  = (const float*)d_in[0];
  const float* wa_f = (const float*)d_in[1];
  const float* ba_f = (const float*)d_in[2];
  const float* wp_f = (const float*)d_in[3];
  const float* bp_f = (const float*)d_in[4];
  float* out = (float*)d_out;

  ushort_t* xb  = (ushort_t*)d_ws;                    // 8192 x  768
  ushort_t* wab = xb  + (size_t)8192 * 768;           // 2304 x  768
  ushort_t* wpb = wab + (size_t)2304 * 768;           //  768 x  768
  ushort_t* QK  = wpb + (size_t)768 * 768;            // 8192 x 1536
  ushort_t* VT  = QK  + (size_t)8192 * 1536;          // 64 x 96 x 1024
  ushort_t* yw  = VT  + (size_t)8192 * 768;           // 8192 x  768

  // (8192*768 + 2304*768 + 768*768)/4 = 2162688 = 8448 * 256
  cvt3<<<8448, 256, 0, stream>>>(x_f, wa_f, wp_f, xb, wab, wpb);

  gemm_qkv<<<dim3(64, 18), 256, 0, stream>>>(xb, wab, ba_f, QK, VT);
  attn_fused<<<dim3(16, 64), 256, 0, stream>>>(QK, VT, yw);
  gemm_proj<<<dim3(64, 6), 256, 0, stream>>>(yw, wpb, bp_f, out,
                                             8192, 768);
}